// Round 3
// baseline (604.146 us; speedup 1.0000x reference)
//
#include <hip/hip_runtime.h>
#include <cstdint>

// Match XLA: no FP contraction (XLA emits separate mul/add HLOs).
#pragma clang fp contract(off)

#define TSAVES 49
#define SPSAVE 100
#define NB 8192
#define NSTEPS (TSAVES * SPSAVE)   // 4900
#define NTOT (NSTEPS * NB)         // 40140800

__device__ __forceinline__ uint32_t rotl32(uint32_t v, int d) {
  return (v << d) | (v >> (32 - d));
}

// JAX threefry2x32, 20 rounds.
__device__ __forceinline__ void tf2x32(uint32_t k0, uint32_t k1,
                                       uint32_t x0, uint32_t x1,
                                       uint32_t& o0, uint32_t& o1) {
  uint32_t ks2 = k0 ^ k1 ^ 0x1BD11BDAu;
#define TF_ROUND(r) { x0 += x1; x1 = rotl32(x1, r); x1 ^= x0; }
  x0 += k0; x1 += k1;
  TF_ROUND(13) TF_ROUND(15) TF_ROUND(26) TF_ROUND(6)
  x0 += k1; x1 += ks2 + 1u;
  TF_ROUND(17) TF_ROUND(29) TF_ROUND(16) TF_ROUND(24)
  x0 += ks2; x1 += k0 + 2u;
  TF_ROUND(13) TF_ROUND(15) TF_ROUND(26) TF_ROUND(6)
  x0 += k0; x1 += k1 + 3u;
  TF_ROUND(17) TF_ROUND(29) TF_ROUND(16) TF_ROUND(24)
  x0 += k1; x1 += ks2 + 4u;
  TF_ROUND(13) TF_ROUND(15) TF_ROUND(26) TF_ROUND(6)
  x0 += ks2; x1 += k0 + 5u;
#undef TF_ROUND
  o0 = x0; o1 = x1;
}

// jax.random.split(key(seed)) with jax_threefry_partitionable=True (modern
// default): fold-like split. Child i = (y0, y1) of threefry(key, hi=0, lo=i).
__device__ __forceinline__ void derive_keys(int seed, uint32_t& kn0, uint32_t& kn1,
                                            uint32_t& ku0, uint32_t& ku1) {
  uint64_t s = (uint64_t)(int64_t)seed;
  uint32_t k0 = (uint32_t)(s >> 32);
  uint32_t k1 = (uint32_t)(s & 0xffffffffULL);
  tf2x32(k0, k1, 0u, 0u, kn0, kn1);  // keys[0] = k_noise
  tf2x32(k0, k1, 0u, 1u, ku0, ku1);  // keys[1] = k_u
}

// partitionable random_bits(32): counter = (hi=0, lo=n); bits = y0 ^ y1.
__device__ __forceinline__ uint32_t rand_bits32(uint32_t k0, uint32_t k1, uint32_t n) {
  uint32_t y0, y1;
  tf2x32(k0, k1, 0u, n, y0, y1);
  return y0 ^ y1;
}

// bits -> dw = sqrt(DT) * (sqrt(2) * erfinv(uniform(nextafter(-1,0), 1)));
// XLA ErfInv32 (Giles). Branchless (select) exactly like XLA's lowering.
__device__ __forceinline__ float bits_to_dw(uint32_t bits) {
  float u01 = __uint_as_float((bits >> 9) | 0x3f800000u) - 1.0f;
  float u = u01 * 2.0f + (-0.99999994f);  // (hi-lo) rounds to 2.0f exactly
  u = fmaxf(-0.99999994f, u);
  float w = -log1pf(-(u * u));

  float z1 = w - 2.5f;
  float p1 = 2.81022636e-08f;
  p1 = 3.43273939e-07f + p1 * z1;
  p1 = -3.5233877e-06f + p1 * z1;
  p1 = -4.39150654e-06f + p1 * z1;
  p1 = 0.00021858087f + p1 * z1;
  p1 = -0.00125372503f + p1 * z1;
  p1 = -0.00417768164f + p1 * z1;
  p1 = 0.246640727f + p1 * z1;
  p1 = 1.50140941f + p1 * z1;

  float z2 = sqrtf(w) - 3.0f;
  float p2 = -0.000200214257f;
  p2 = 0.000100950558f + p2 * z2;
  p2 = 0.00134934322f + p2 * z2;
  p2 = -0.00367342844f + p2 * z2;
  p2 = 0.00573950773f + p2 * z2;
  p2 = -0.0076224613f + p2 * z2;
  p2 = 0.00943887047f + p2 * z2;
  p2 = 1.00167406f + p2 * z2;
  p2 = 2.83297682f + p2 * z2;

  float p = (w < 5.0f) ? p1 : p2;
  float ei = p * u;
  float nrm = 1.41421356f * ei;  // f32(np.sqrt(2))
  return nrm * 0.1f;             // * sqrt(f32(0.01)) == 0.1f exactly
}

#define GEN_BLOCKS 2048
// 4 interleaved samples/thread (independent threefry chains pipeline), float4
// store, grid-stride. Key derivation is wave-uniform -> scalarized by compiler.
__global__ __launch_bounds__(256) void gen_noise_kernel(const int* __restrict__ seedp,
                                                        float* __restrict__ noise) {
  uint32_t kn0, kn1, ku0, ku1;
  derive_keys(seedp[0], kn0, kn1, ku0, ku1);
  const uint32_t nthreads = GEN_BLOCKS * 256u;
  for (uint32_t q = blockIdx.x * 256u + threadIdx.x; q < (uint32_t)(NTOT / 4); q += nthreads) {
    uint32_t n = q * 4u;
    float4 o;
    o.x = bits_to_dw(rand_bits32(kn0, kn1, n + 0u));
    o.y = bits_to_dw(rand_bits32(kn0, kn1, n + 1u));
    o.z = bits_to_dw(rand_bits32(kn0, kn1, n + 2u));
    o.w = bits_to_dw(rand_bits32(kn0, kn1, n + 3u));
    *reinterpret_cast<float4*>(noise + n) = o;
  }
}

__device__ __forceinline__ float clip_param(float x) {
  return fminf(0.99999988f, fmaxf(1e-07f, x));
}

// One Euler step; XLA op order preserved (contraction disabled file-wide).
#define SIM_STEP(dw_) { \
    float ni = (r0 * prec) * s; \
    float nr = prec * i; \
    float s_n = s - 0.01f * ni; \
    float i_n = i + 0.01f * (ni - nr); \
    float r0_n = (r0 + dtmr * (r0m - r0)) + ((sqrtf(fabsf(r0)) * pvol) * (dw_)); \
    s = s_n; i = i_n; r0 = r0_n; }

#define LOADG(arr, g) { \
    _Pragma("unroll") \
    for (int k = 0; k < 10; ++k) arr[k] = buf[cur][((g) * 10 + k) * 64 + lane]; }

#define COMPG(arr) { \
    _Pragma("unroll") \
    for (int k = 0; k < 10; ++k) SIM_STEP(arr[k]); }

template <bool FLY>
__global__ __launch_bounds__(64) void sim_kernel(const float* __restrict__ cond,
                                                 const int* __restrict__ seedp,
                                                 const float* __restrict__ noise,
                                                 float* __restrict__ out) {
  __shared__ __align__(16) float buf[2][SPSAVE * 64];
  const int lane = threadIdx.x;
  const int b0 = blockIdx.x * 64;
  const int b = b0 + lane;

  uint32_t kn0, kn1, ku0, ku1;
  derive_keys(seedp[0], kn0, kn1, ku0, ku1);

  float pinf = clip_param(cond[b * 4 + 0]);
  float prec = clip_param(cond[b * 4 + 1]);
  float pmr  = clip_param(cond[b * 4 + 2]);
  float pvol = clip_param(cond[b * 4 + 3]);

  float r0m = pinf / prec;
  float dtmr = 0.01f * pmr;

  float s = 0.99f, i = 0.01f, r0 = r0m;

  float best = -1.0f; int bi = 0;
  float plg = 0.0f, sd = 0.0f, sd2 = 0.0f;

  const int r = lane >> 4;          // row within 4-row group (width-16 staging)
  const int c = (lane & 15) << 2;   // float col within row

  if (!FLY) {
    for (int j4 = 0; j4 < 25; ++j4) {
      const float* g = noise + (size_t)(j4 * 4 + r) * NB + b0 + c;
      __builtin_amdgcn_global_load_lds(
          (const __attribute__((address_space(1))) void*)g,
          (__attribute__((address_space(3))) void*)(&buf[0][j4 * 256]),
          16, 0, 0);
    }
    __syncthreads();
  }

  for (int t = 0; t < TSAVES; ++t) {
    const int cur = t & 1;
    if (!FLY && t + 1 < TSAVES) {
      const int nxt = cur ^ 1;
      for (int j4 = 0; j4 < 25; ++j4) {
        const float* g = noise + (size_t)((t + 1) * SPSAVE + j4 * 4 + r) * NB + b0 + c;
        __builtin_amdgcn_global_load_lds(
            (const __attribute__((address_space(1))) void*)g,
            (__attribute__((address_space(3))) void*)(&buf[nxt][j4 * 256]),
            16, 0, 0);
      }
    }
    if (FLY) {
#pragma unroll 10
      for (int j = 0; j < SPSAVE; ++j) {
        uint32_t n = (uint32_t)(t * SPSAVE + j) * (uint32_t)NB + (uint32_t)b;
        float dw = bits_to_dw(rand_bits32(kn0, kn1, n));
        SIM_STEP(dw);
      }
    } else {
      // Register-prefetched, double-buffered groups of 10 ds_read_b32.
      // All indices compile-time constant (no scratch; rule #20).
      float dwsA[10], dwsB[10];
      LOADG(dwsA, 0);
      LOADG(dwsB, 1); COMPG(dwsA);
      LOADG(dwsA, 2); COMPG(dwsB);
      LOADG(dwsB, 3); COMPG(dwsA);
      LOADG(dwsA, 4); COMPG(dwsB);
      LOADG(dwsB, 5); COMPG(dwsA);
      LOADG(dwsA, 6); COMPG(dwsB);
      LOADG(dwsB, 7); COMPG(dwsA);
      LOADG(dwsA, 8); COMPG(dwsB);
      LOADG(dwsB, 9); COMPG(dwsA);
      COMPG(dwsB);
    }
    // save i, nan_to_num, streaming summarize
    float v = i;
    if (!isfinite(v)) v = 0.0f;
    float x = fmaxf(v, 1e-05f);
    if (x > best) { best = x; bi = t; }
    float lg = logf(x);
    if (t > 0) { float d = lg - plg; sd += d; sd2 += d * d; }
    plg = lg;
    if (!FLY) __syncthreads();  // single wave: just the waitcnt drain
  }

  // u = uniform(k_u, (B,)) in [0,1): bits = y0^y1 of tf(ku, (0, b))
  uint32_t ub = rand_bits32(ku0, ku1, (uint32_t)b);
  float u = __uint_as_float((ub >> 9) | 0x3f800000u) - 1.0f;
  u = fmaxf(0.0f, u);

  float maxat = ((float)bi + u) / 49.0f;
  float mean = sd / 48.0f;
  float var = sd2 / 48.0f - mean * mean;
  float stdv = sqrtf(fmaxf(var, 0.0f));

  out[b * 3 + 0] = (best  - 0.38f) / 0.14f;
  out[b * 3 + 1] = (maxat - 0.21f) / 0.12f;
  out[b * 3 + 2] = (stdv  - 0.14f) / 0.03f;
}

extern "C" void kernel_launch(void* const* d_in, const int* in_sizes, int n_in,
                              void* d_out, int out_size, void* d_ws, size_t ws_size,
                              hipStream_t stream) {
  const float* cond = (const float*)d_in[0];
  const int* seedp = (const int*)d_in[1];
  float* out = (float*)d_out;
  float* noise = (float*)d_ws;
  const size_t need = (size_t)NTOT * sizeof(float);
  if (ws_size >= need) {
    gen_noise_kernel<<<GEN_BLOCKS, 256, 0, stream>>>(seedp, noise);
    sim_kernel<false><<<NB / 64, 64, 0, stream>>>(cond, seedp, noise, out);
  } else {
    sim_kernel<true><<<NB / 64, 64, 0, stream>>>(cond, seedp, nullptr, out);
  }
}

// Round 4
// 395.548 us; speedup vs baseline: 1.5274x; 1.5274x over previous
//
#include <hip/hip_runtime.h>
#include <cstdint>

// Match XLA: no FP contraction (XLA emits separate mul/add HLOs).
#pragma clang fp contract(off)

#define TSAVES 49
#define SPSAVE 100
#define NB 8192
#define NSTEPS (TSAVES * SPSAVE)   // 4900
#define NTOT (NSTEPS * NB)         // 40140800

__device__ __forceinline__ uint32_t rotl32(uint32_t v, int d) {
  return (v << d) | (v >> (32 - d));
}

// JAX threefry2x32, 20 rounds.
__device__ __forceinline__ void tf2x32(uint32_t k0, uint32_t k1,
                                       uint32_t x0, uint32_t x1,
                                       uint32_t& o0, uint32_t& o1) {
  uint32_t ks2 = k0 ^ k1 ^ 0x1BD11BDAu;
#define TF_ROUND(r) { x0 += x1; x1 = rotl32(x1, r); x1 ^= x0; }
  x0 += k0; x1 += k1;
  TF_ROUND(13) TF_ROUND(15) TF_ROUND(26) TF_ROUND(6)
  x0 += k1; x1 += ks2 + 1u;
  TF_ROUND(17) TF_ROUND(29) TF_ROUND(16) TF_ROUND(24)
  x0 += ks2; x1 += k0 + 2u;
  TF_ROUND(13) TF_ROUND(15) TF_ROUND(26) TF_ROUND(6)
  x0 += k0; x1 += k1 + 3u;
  TF_ROUND(17) TF_ROUND(29) TF_ROUND(16) TF_ROUND(24)
  x0 += k1; x1 += ks2 + 4u;
  TF_ROUND(13) TF_ROUND(15) TF_ROUND(26) TF_ROUND(6)
  x0 += ks2; x1 += k0 + 5u;
#undef TF_ROUND
  o0 = x0; o1 = x1;
}

// jax.random.split(key(seed)), jax_threefry_partitionable=True (fold-like).
__device__ __forceinline__ void derive_keys(int seed, uint32_t& kn0, uint32_t& kn1,
                                            uint32_t& ku0, uint32_t& ku1) {
  uint64_t s = (uint64_t)(int64_t)seed;
  uint32_t k0 = (uint32_t)(s >> 32);
  uint32_t k1 = (uint32_t)(s & 0xffffffffULL);
  tf2x32(k0, k1, 0u, 0u, kn0, kn1);  // keys[0] = k_noise
  tf2x32(k0, k1, 0u, 1u, ku0, ku1);  // keys[1] = k_u
}

// partitionable random_bits(32): counter = (hi=0, lo=n); bits = y0 ^ y1.
__device__ __forceinline__ uint32_t rand_bits32(uint32_t k0, uint32_t k1, uint32_t n) {
  uint32_t y0, y1;
  tf2x32(k0, k1, 0u, n, y0, y1);
  return y0 ^ y1;
}

// bits -> dw; XLA ErfInv32 (Giles). Branchy: wave takes the w>=5 path only if
// some lane needs it (~0.2% of waves) -> execz skip. Identical values to the
// branchless select (round-2/3 both measured absmax 1.038e34).
__device__ __forceinline__ float bits_to_dw(uint32_t bits) {
  float u01 = __uint_as_float((bits >> 9) | 0x3f800000u) - 1.0f;
  float u = u01 * 2.0f + (-0.99999994f);  // (hi-lo) rounds to 2.0f exactly
  u = fmaxf(-0.99999994f, u);
  float w = -log1pf(-(u * u));
  float p;
  if (w < 5.0f) {
    float z = w - 2.5f;
    p = 2.81022636e-08f;
    p = 3.43273939e-07f + p * z;
    p = -3.5233877e-06f + p * z;
    p = -4.39150654e-06f + p * z;
    p = 0.00021858087f + p * z;
    p = -0.00125372503f + p * z;
    p = -0.00417768164f + p * z;
    p = 0.246640727f + p * z;
    p = 1.50140941f + p * z;
  } else {
    float z = sqrtf(w) - 3.0f;
    p = -0.000200214257f;
    p = 0.000100950558f + p * z;
    p = 0.00134934322f + p * z;
    p = -0.00367342844f + p * z;
    p = 0.00573950773f + p * z;
    p = -0.0076224613f + p * z;
    p = 0.00943887047f + p * z;
    p = 1.00167406f + p * z;
    p = 2.83297682f + p * z;
  }
  float ei = p * u;
  float nrm = 1.41421356f * ei;  // f32(np.sqrt(2))
  return nrm * 0.1f;             // * sqrt(f32(0.01)) == 0.1f exactly
}

// Round-2 gen (166 us known-good): shared keys, 1 sample/thread, branchy.
__global__ __launch_bounds__(256) void gen_noise_kernel(const int* __restrict__ seedp,
                                                        float* __restrict__ noise) {
  __shared__ uint32_t sk[2];
  if (threadIdx.x == 0) {
    uint32_t kn0, kn1, ku0, ku1;
    derive_keys(seedp[0], kn0, kn1, ku0, ku1);
    sk[0] = kn0; sk[1] = kn1;
  }
  __syncthreads();
  uint32_t kn0 = sk[0], kn1 = sk[1];
  uint32_t n = blockIdx.x * 256u + threadIdx.x;
  if (n < (uint32_t)NTOT) {
    noise[n] = bits_to_dw(rand_bits32(kn0, kn1, n));
  }
}

__device__ __forceinline__ float clip_param(float x) {
  return fminf(0.99999988f, fmaxf(1e-07f, x));
}

template <bool FLY>
__global__ __launch_bounds__(64) void sim_kernel(const float* __restrict__ cond,
                                                 const int* __restrict__ seedp,
                                                 const float* __restrict__ noise,
                                                 float* __restrict__ out) {
  const int lane = threadIdx.x;
  const int b = blockIdx.x * 64 + lane;

  uint32_t kn0, kn1, ku0, ku1;
  derive_keys(seedp[0], kn0, kn1, ku0, ku1);

  float pinf = clip_param(cond[b * 4 + 0]);
  float prec = clip_param(cond[b * 4 + 1]);
  float pmr  = clip_param(cond[b * 4 + 2]);
  float pvol = clip_param(cond[b * 4 + 3]);

  float r0m = pinf / prec;
  float dtmr = 0.01f * pmr;

  float s = 0.99f, i = 0.01f, r0 = r0m;

  float best = -1.0f; int bi = 0;
  float plg = 0.0f, sd = 0.0f, sd2 = 0.0f;

  if (FLY) {
    for (int t = 0; t < TSAVES; ++t) {
#pragma unroll 10
      for (int j = 0; j < SPSAVE; ++j) {
        uint32_t n = (uint32_t)(t * SPSAVE + j) * (uint32_t)NB + (uint32_t)b;
        float dw = bits_to_dw(rand_bits32(kn0, kn1, n));
        float ni = (r0 * prec) * s;
        float nr = prec * i;
        float s_n = s - 0.01f * ni;
        float i_n = i + 0.01f * (ni - nr);
        float r0_n = (r0 + dtmr * (r0m - r0)) + ((sqrtf(fabsf(r0)) * pvol) * dw);
        s = s_n; i = i_n; r0 = r0_n;
      }
      float v = i;
      if (!isfinite(v)) v = 0.0f;
      float x = fmaxf(v, 1e-05f);
      if (x > best) { best = x; bi = t; }
      float lg = logf(x);
      if (t > 0) { float d = lg - plg; sd += d; sd2 += d * d; }
      plg = lg;
    }
  } else {
    // Direct global->register noise stream. Groups of 25 steps, 2 in flight
    // (<=50 outstanding VMEM; counted vmcnt by compiler). Each group is
    // issued ~2 compute-groups (~1400 cy) before its first use -> HBM/L3
    // latency fully hidden. sched_barrier(0) pins the pipeline structure.
    const float* pb = noise + b;
    float gA[25], gB[25];
#define ISSUE(buf, s0) { \
    _Pragma("unroll") \
    for (int k = 0; k < 25; ++k) buf[k] = pb[(size_t)((s0) + k) * NB]; \
    __builtin_amdgcn_sched_barrier(0); }
    // One Euler step; XLA op order except: raw v_sqrt_f32 (<=1ulp) and
    // pvol*dw pre-folded off the r0 chain (1-ulp reassociation).
#define CGRP(buf) { \
    _Pragma("unroll") \
    for (int k = 0; k < 25; ++k) { \
      float vdw = buf[k] * pvol; \
      float ni = (r0 * prec) * s; \
      float nr = prec * i; \
      float s_n = s - 0.01f * ni; \
      float i_n = i + 0.01f * (ni - nr); \
      float sq = __builtin_amdgcn_sqrtf(fabsf(r0)); \
      float r0_n = (r0 + dtmr * (r0m - r0)) + (sq * vdw); \
      s = s_n; i = i_n; r0 = r0_n; \
    } \
    __builtin_amdgcn_sched_barrier(0); }

    ISSUE(gA, 0);
    ISSUE(gB, 25);
    for (int t = 0; t < TSAVES; ++t) {
      const int base = t * SPSAVE;
      const int n1 = (base + 50  <= NSTEPS - 25) ? base + 50  : NSTEPS - 25;
      const int n2 = (base + 75  <= NSTEPS - 25) ? base + 75  : NSTEPS - 25;
      const int n3 = (base + 100 <= NSTEPS - 25) ? base + 100 : NSTEPS - 25;
      const int n4 = (base + 125 <= NSTEPS - 25) ? base + 125 : NSTEPS - 25;
      CGRP(gA); ISSUE(gA, n1);
      CGRP(gB); ISSUE(gB, n2);
      CGRP(gA); ISSUE(gA, n3);
      CGRP(gB); ISSUE(gB, n4);
      // save i, nan_to_num, streaming summarize
      float v = i;
      if (!isfinite(v)) v = 0.0f;
      float x = fmaxf(v, 1e-05f);
      if (x > best) { best = x; bi = t; }
      float lg = logf(x);
      if (t > 0) { float d = lg - plg; sd += d; sd2 += d * d; }
      plg = lg;
    }
#undef ISSUE
#undef CGRP
  }

  // u = uniform(k_u, (B,)) in [0,1): bits = y0^y1 of tf(ku, (0, b))
  uint32_t ub = rand_bits32(ku0, ku1, (uint32_t)b);
  float u = __uint_as_float((ub >> 9) | 0x3f800000u) - 1.0f;
  u = fmaxf(0.0f, u);

  float maxat = ((float)bi + u) / 49.0f;
  float mean = sd / 48.0f;
  float var = sd2 / 48.0f - mean * mean;
  float stdv = sqrtf(fmaxf(var, 0.0f));

  out[b * 3 + 0] = (best  - 0.38f) / 0.14f;
  out[b * 3 + 1] = (maxat - 0.21f) / 0.12f;
  out[b * 3 + 2] = (stdv  - 0.14f) / 0.03f;
}

extern "C" void kernel_launch(void* const* d_in, const int* in_sizes, int n_in,
                              void* d_out, int out_size, void* d_ws, size_t ws_size,
                              hipStream_t stream) {
  const float* cond = (const float*)d_in[0];
  const int* seedp = (const int*)d_in[1];
  float* out = (float*)d_out;
  float* noise = (float*)d_ws;
  const size_t need = (size_t)NTOT * sizeof(float);
  if (ws_size >= need) {
    gen_noise_kernel<<<(NTOT + 255) / 256, 256, 0, stream>>>(seedp, noise);
    sim_kernel<false><<<NB / 64, 64, 0, stream>>>(cond, seedp, noise, out);
  } else {
    sim_kernel<true><<<NB / 64, 64, 0, stream>>>(cond, seedp, nullptr, out);
  }
}

// Round 5
// 343.559 us; speedup vs baseline: 1.7585x; 1.1513x over previous
//
#include <hip/hip_runtime.h>
#include <cstdint>

// Match XLA: no FP contraction by default (XLA emits separate mul/add HLOs).
// bits_to_dw locally enables contraction — measured-safe (absmax insensitive).
#pragma clang fp contract(off)

#define TSAVES 49
#define SPSAVE 100
#define NB 8192
#define NSTEPS (TSAVES * SPSAVE)   // 4900
#define NTOT (NSTEPS * NB)         // 40140800

__device__ __forceinline__ uint32_t rotl32(uint32_t v, int d) {
  return (v << d) | (v >> (32 - d));
}

// JAX threefry2x32, 20 rounds.
__device__ __forceinline__ void tf2x32(uint32_t k0, uint32_t k1,
                                       uint32_t x0, uint32_t x1,
                                       uint32_t& o0, uint32_t& o1) {
  uint32_t ks2 = k0 ^ k1 ^ 0x1BD11BDAu;
#define TF_ROUND(r) { x0 += x1; x1 = rotl32(x1, r); x1 ^= x0; }
  x0 += k0; x1 += k1;
  TF_ROUND(13) TF_ROUND(15) TF_ROUND(26) TF_ROUND(6)
  x0 += k1; x1 += ks2 + 1u;
  TF_ROUND(17) TF_ROUND(29) TF_ROUND(16) TF_ROUND(24)
  x0 += ks2; x1 += k0 + 2u;
  TF_ROUND(13) TF_ROUND(15) TF_ROUND(26) TF_ROUND(6)
  x0 += k0; x1 += k1 + 3u;
  TF_ROUND(17) TF_ROUND(29) TF_ROUND(16) TF_ROUND(24)
  x0 += k1; x1 += ks2 + 4u;
  TF_ROUND(13) TF_ROUND(15) TF_ROUND(26) TF_ROUND(6)
  x0 += ks2; x1 += k0 + 5u;
#undef TF_ROUND
  o0 = x0; o1 = x1;
}

// jax.random.split(key(seed)), jax_threefry_partitionable=True (fold-like).
__device__ __forceinline__ void derive_keys(int seed, uint32_t& kn0, uint32_t& kn1,
                                            uint32_t& ku0, uint32_t& ku1) {
  uint64_t s = (uint64_t)(int64_t)seed;
  uint32_t k0 = (uint32_t)(s >> 32);
  uint32_t k1 = (uint32_t)(s & 0xffffffffULL);
  tf2x32(k0, k1, 0u, 0u, kn0, kn1);  // keys[0] = k_noise
  tf2x32(k0, k1, 0u, 1u, ku0, ku1);  // keys[1] = k_u
}

// partitionable random_bits(32): counter = (hi=0, lo=n); bits = y0 ^ y1.
__device__ __forceinline__ uint32_t rand_bits32(uint32_t k0, uint32_t k1, uint32_t n) {
  uint32_t y0, y1;
  tf2x32(k0, k1, 0u, n, y0, y1);
  return y0 ^ y1;
}

// bits -> dw; XLA ErfInv32 (Giles). Branchy tail (execz-skipped ~80% of waves).
// Local contraction + hardware log2: <=1e-7 absolute shift in w — measured
// headroom (absmax pinned at 1.038e34 across 3 rounds of ulp-level changes).
__device__ __forceinline__ float bits_to_dw(uint32_t bits) {
#pragma clang fp contract(fast)
  float u01 = __uint_as_float((bits >> 9) | 0x3f800000u) - 1.0f;
  float u = u01 * 2.0f + (-0.99999994f);
  u = fmaxf(-0.99999994f, u);
  float omu2 = 1.0f - u * u;                       // fma(-u,u,1): exact-ish
  float w = -(__builtin_amdgcn_logf(omu2) * 0.6931472f);  // v_log (log2) * ln2
  float p;
  if (w < 5.0f) {
    float z = w - 2.5f;
    p = 2.81022636e-08f;
    p = 3.43273939e-07f + p * z;
    p = -3.5233877e-06f + p * z;
    p = -4.39150654e-06f + p * z;
    p = 0.00021858087f + p * z;
    p = -0.00125372503f + p * z;
    p = -0.00417768164f + p * z;
    p = 0.246640727f + p * z;
    p = 1.50140941f + p * z;
  } else {
    float z = __builtin_amdgcn_sqrtf(w) - 3.0f;
    p = -0.000200214257f;
    p = 0.000100950558f + p * z;
    p = 0.00134934322f + p * z;
    p = -0.00367342844f + p * z;
    p = 0.00573950773f + p * z;
    p = -0.0076224613f + p * z;
    p = 0.00943887047f + p * z;
    p = 1.00167406f + p * z;
    p = 2.83297682f + p * z;
  }
  float ei = p * u;
  float nrm = 1.41421356f * ei;  // f32(np.sqrt(2))
  return nrm * 0.1f;             // * sqrt(f32(0.01)) == 0.1f exactly
}

#define GEN_BLOCKS 2048
// Grid-stride, per-thread key (amortized over ~76 samples), 4 samples/iter,
// float4 stores, branchy erfinv (round-3 lesson: branchless = +50% ops).
__global__ __launch_bounds__(256) void gen_noise_kernel(const int* __restrict__ seedp,
                                                        float* __restrict__ noise) {
  uint64_t sdv = (uint64_t)(int64_t)seedp[0];
  uint32_t k0 = (uint32_t)(sdv >> 32), k1 = (uint32_t)sdv;
  uint32_t kn0, kn1;
  tf2x32(k0, k1, 0u, 0u, kn0, kn1);
  const uint32_t stride = GEN_BLOCKS * 256u;
  for (uint32_t q = blockIdx.x * 256u + threadIdx.x; q < (uint32_t)(NTOT / 4); q += stride) {
    uint32_t n = q * 4u;
    float4 o;
    o.x = bits_to_dw(rand_bits32(kn0, kn1, n + 0u));
    o.y = bits_to_dw(rand_bits32(kn0, kn1, n + 1u));
    o.z = bits_to_dw(rand_bits32(kn0, kn1, n + 2u));
    o.w = bits_to_dw(rand_bits32(kn0, kn1, n + 3u));
    *reinterpret_cast<float4*>(noise + n) = o;
  }
}

__device__ __forceinline__ float clip_param(float x) {
  return fminf(0.99999988f, fmaxf(1e-07f, x));
}

template <bool FLY>
__global__ __launch_bounds__(64, 1) void sim_kernel(const float* __restrict__ cond,
                                                    const int* __restrict__ seedp,
                                                    const float* __restrict__ noise,
                                                    float* __restrict__ out) {
  const int lane = threadIdx.x;
  const int b = blockIdx.x * 64 + lane;

  uint32_t kn0, kn1, ku0, ku1;
  derive_keys(seedp[0], kn0, kn1, ku0, ku1);

  float pinf = clip_param(cond[b * 4 + 0]);
  float prec = clip_param(cond[b * 4 + 1]);
  float pmr  = clip_param(cond[b * 4 + 2]);
  float pvol = clip_param(cond[b * 4 + 3]);

  float r0m = pinf / prec;
  float dtmr = 0.01f * pmr;

  float s = 0.99f, i = 0.01f, r0 = r0m;

  float best = -1.0f; int bi = 0;
  float plg = 0.0f, sd = 0.0f, sd2 = 0.0f;

  if (FLY) {
    for (int t = 0; t < TSAVES; ++t) {
#pragma unroll 10
      for (int j = 0; j < SPSAVE; ++j) {
        uint32_t n = (uint32_t)(t * SPSAVE + j) * (uint32_t)NB + (uint32_t)b;
        float dw = bits_to_dw(rand_bits32(kn0, kn1, n));
        float ni = (r0 * prec) * s;
        float nr = prec * i;
        float s_n = s - 0.01f * ni;
        float i_n = i + 0.01f * (ni - nr);
        float r0_n = (r0 + dtmr * (r0m - r0)) + ((sqrtf(fabsf(r0)) * pvol) * dw);
        s = s_n; i = i_n; r0 = r0_n;
      }
      float v = i;
      if (!isfinite(v)) v = 0.0f;
      float x = fmaxf(v, 1e-05f);
      if (x > best) { best = x; bi = t; }
      float lg = logf(x);
      if (t > 0) { float d = lg - plg; sd += d; sd2 += d * d; }
      plg = lg;
    }
  } else {
    // Direct global->register noise stream. 4 buffers x 25 steps; group m is
    // issued 3 compute-groups (~1800 cy) before use -> covers ~900 cy HBM-miss
    // latency (m126). Peak outstanding VMEM = 50 <= vmcnt limit 63 -> no
    // issue-stall. sched_barrier(0) pins the pipeline structure.
    const float* pb = noise + b;
    float q0[25], q1[25], q2[25], q3[25];
#define ISSUE(buf, s0) { \
    const int s0c = ((s0) > NSTEPS - 25) ? (NSTEPS - 25) : (s0); \
    _Pragma("unroll") \
    for (int k = 0; k < 25; ++k) buf[k] = pb[(size_t)(s0c + k) * NB]; \
    __builtin_amdgcn_sched_barrier(0); }
    // One Euler step; XLA op order except raw v_sqrt_f32 (<=1ulp) and
    // pvol*dw pre-folded off the r0 chain (1-ulp reassociation).
#define CGRP(buf) { \
    _Pragma("unroll") \
    for (int k = 0; k < 25; ++k) { \
      float vdw = buf[k] * pvol; \
      float ni = (r0 * prec) * s; \
      float nr = prec * i; \
      float s_n = s - 0.01f * ni; \
      float i_n = i + 0.01f * (ni - nr); \
      float sq = __builtin_amdgcn_sqrtf(fabsf(r0)); \
      float r0_n = (r0 + dtmr * (r0m - r0)) + (sq * vdw); \
      s = s_n; i = i_n; r0 = r0_n; \
    } \
    __builtin_amdgcn_sched_barrier(0); }

    ISSUE(q0, 0);
    ISSUE(q1, 25);
    ISSUE(q2, 50);
    for (int t = 0; t < TSAVES; ++t) {
      const int base = t * SPSAVE;
      ISSUE(q3, base + 75);  CGRP(q0);
      ISSUE(q0, base + 100); CGRP(q1);
      ISSUE(q1, base + 125); CGRP(q2);
      ISSUE(q2, base + 150); CGRP(q3);
      // save i, nan_to_num, streaming summarize
      float v = i;
      if (!isfinite(v)) v = 0.0f;
      float x = fmaxf(v, 1e-05f);
      if (x > best) { best = x; bi = t; }
      float lg = logf(x);
      if (t > 0) { float d = lg - plg; sd += d; sd2 += d * d; }
      plg = lg;
    }
#undef ISSUE
#undef CGRP
  }

  // u = uniform(k_u, (B,)) in [0,1): bits = y0^y1 of tf(ku, (0, b))
  uint32_t ub = rand_bits32(ku0, ku1, (uint32_t)b);
  float u = __uint_as_float((ub >> 9) | 0x3f800000u) - 1.0f;
  u = fmaxf(0.0f, u);

  float maxat = ((float)bi + u) / 49.0f;
  float mean = sd / 48.0f;
  float var = sd2 / 48.0f - mean * mean;
  float stdv = sqrtf(fmaxf(var, 0.0f));

  out[b * 3 + 0] = (best  - 0.38f) / 0.14f;
  out[b * 3 + 1] = (maxat - 0.21f) / 0.12f;
  out[b * 3 + 2] = (stdv  - 0.14f) / 0.03f;
}

extern "C" void kernel_launch(void* const* d_in, const int* in_sizes, int n_in,
                              void* d_out, int out_size, void* d_ws, size_t ws_size,
                              hipStream_t stream) {
  const float* cond = (const float*)d_in[0];
  const int* seedp = (const int*)d_in[1];
  float* out = (float*)d_out;
  float* noise = (float*)d_ws;
  const size_t need = (size_t)NTOT * sizeof(float);
  if (ws_size >= need) {
    gen_noise_kernel<<<GEN_BLOCKS, 256, 0, stream>>>(seedp, noise);
    sim_kernel<false><<<NB / 64, 64, 0, stream>>>(cond, seedp, noise, out);
  } else {
    sim_kernel<true><<<NB / 64, 64, 0, stream>>>(cond, seedp, nullptr, out);
  }
}

// Round 6
// 284.532 us; speedup vs baseline: 2.1233x; 1.2075x over previous
//
#include <hip/hip_runtime.h>
#include <cstdint>

// XLA emits separate mul/add; keep contraction off by default. Hot paths use
// explicit fmaf()/hw-transcendentals — measured-safe (absmax pinned at
// 1.038459e34 across 3 rounds of ulp-level arithmetic changes; slack ~3.5x).
#pragma clang fp contract(off)

#define TSAVES 49
#define SPSAVE 100
#define NB 8192
#define NSTEPS (TSAVES * SPSAVE)   // 4900
#define NTOT (NSTEPS * NB)         // 40140800

__device__ __forceinline__ uint32_t rotl32(uint32_t v, int d) {
  return (v << d) | (v >> (32 - d));
}

// JAX threefry2x32, 20 rounds.
__device__ __forceinline__ void tf2x32(uint32_t k0, uint32_t k1,
                                       uint32_t x0, uint32_t x1,
                                       uint32_t& o0, uint32_t& o1) {
  uint32_t ks2 = k0 ^ k1 ^ 0x1BD11BDAu;
#define TF_ROUND(r) { x0 += x1; x1 = rotl32(x1, r); x1 ^= x0; }
  x0 += k0; x1 += k1;
  TF_ROUND(13) TF_ROUND(15) TF_ROUND(26) TF_ROUND(6)
  x0 += k1; x1 += ks2 + 1u;
  TF_ROUND(17) TF_ROUND(29) TF_ROUND(16) TF_ROUND(24)
  x0 += ks2; x1 += k0 + 2u;
  TF_ROUND(13) TF_ROUND(15) TF_ROUND(26) TF_ROUND(6)
  x0 += k0; x1 += k1 + 3u;
  TF_ROUND(17) TF_ROUND(29) TF_ROUND(16) TF_ROUND(24)
  x0 += k1; x1 += ks2 + 4u;
  TF_ROUND(13) TF_ROUND(15) TF_ROUND(26) TF_ROUND(6)
  x0 += ks2; x1 += k0 + 5u;
#undef TF_ROUND
  o0 = x0; o1 = x1;
}

// jax.random.split(key(seed)), jax_threefry_partitionable=True (fold-like).
__device__ __forceinline__ void derive_keys(int seed, uint32_t& kn0, uint32_t& kn1,
                                            uint32_t& ku0, uint32_t& ku1) {
  uint64_t s = (uint64_t)(int64_t)seed;
  uint32_t k0 = (uint32_t)(s >> 32);
  uint32_t k1 = (uint32_t)(s & 0xffffffffULL);
  tf2x32(k0, k1, 0u, 0u, kn0, kn1);  // keys[0] = k_noise
  tf2x32(k0, k1, 0u, 1u, ku0, ku1);  // keys[1] = k_u
}

// partitionable random_bits(32): counter = (hi=0, lo=n); bits = y0 ^ y1.
__device__ __forceinline__ uint32_t rand_bits32(uint32_t k0, uint32_t k1, uint32_t n) {
  uint32_t y0, y1;
  tf2x32(k0, k1, 0u, n, y0, y1);
  return y0 ^ y1;
}

// bits -> dw; XLA ErfInv32 (Giles). Branchy tail (execz-skipped ~80% of waves).
__device__ __forceinline__ float bits_to_dw(uint32_t bits) {
#pragma clang fp contract(fast)
  float u01 = __uint_as_float((bits >> 9) | 0x3f800000u) - 1.0f;
  float u = u01 * 2.0f + (-0.99999994f);
  u = fmaxf(-0.99999994f, u);
  float omu2 = 1.0f - u * u;                       // fma(-u,u,1)
  float w = -(__builtin_amdgcn_logf(omu2) * 0.6931472f);  // v_log (log2) * ln2
  float p;
  if (w < 5.0f) {
    float z = w - 2.5f;
    p = 2.81022636e-08f;
    p = 3.43273939e-07f + p * z;
    p = -3.5233877e-06f + p * z;
    p = -4.39150654e-06f + p * z;
    p = 0.00021858087f + p * z;
    p = -0.00125372503f + p * z;
    p = -0.00417768164f + p * z;
    p = 0.246640727f + p * z;
    p = 1.50140941f + p * z;
  } else {
    float z = __builtin_amdgcn_sqrtf(w) - 3.0f;
    p = -0.000200214257f;
    p = 0.000100950558f + p * z;
    p = 0.00134934322f + p * z;
    p = -0.00367342844f + p * z;
    p = 0.00573950773f + p * z;
    p = -0.0076224613f + p * z;
    p = 0.00943887047f + p * z;
    p = 1.00167406f + p * z;
    p = 2.83297682f + p * z;
  }
  float ei = p * u;
  float nrm = 1.41421356f * ei;  // f32(np.sqrt(2))
  return nrm * 0.1f;             // * sqrt(f32(0.01)) == 0.1f exactly
}

#define GEN_BLOCKS 4096
// Grid-stride, per-thread key, 4 samples/iter, float4 stores, branchy erfinv.
__global__ __launch_bounds__(256) void gen_noise_kernel(const int* __restrict__ seedp,
                                                        float* __restrict__ noise) {
  uint64_t sdv = (uint64_t)(int64_t)seedp[0];
  uint32_t k0 = (uint32_t)(sdv >> 32), k1 = (uint32_t)sdv;
  uint32_t kn0, kn1;
  tf2x32(k0, k1, 0u, 0u, kn0, kn1);
  const uint32_t stride = GEN_BLOCKS * 256u;
  for (uint32_t q = blockIdx.x * 256u + threadIdx.x; q < (uint32_t)(NTOT / 4); q += stride) {
    uint32_t n = q * 4u;
    float4 o;
    o.x = bits_to_dw(rand_bits32(kn0, kn1, n + 0u));
    o.y = bits_to_dw(rand_bits32(kn0, kn1, n + 1u));
    o.z = bits_to_dw(rand_bits32(kn0, kn1, n + 2u));
    o.w = bits_to_dw(rand_bits32(kn0, kn1, n + 3u));
    *reinterpret_cast<float4*>(noise + n) = o;
  }
}

__device__ __forceinline__ float clip_param(float x) {
  return fminf(0.99999988f, fmaxf(1e-07f, x));
}

template <bool FLY>
__global__ __launch_bounds__(64, 1) void sim_kernel(const float* __restrict__ cond,
                                                    const int* __restrict__ seedp,
                                                    const float* __restrict__ noise,
                                                    float* __restrict__ out) {
  const int lane = threadIdx.x;
  const int b = blockIdx.x * 64 + lane;

  uint32_t kn0, kn1, ku0, ku1;
  derive_keys(seedp[0], kn0, kn1, ku0, ku1);

  float pinf = clip_param(cond[b * 4 + 0]);
  float prec = clip_param(cond[b * 4 + 1]);
  float pmr  = clip_param(cond[b * 4 + 2]);
  float pvol = clip_param(cond[b * 4 + 3]);

  float r0m = pinf / prec;
  float dtmr = 0.01f * pmr;

  float s = 0.99f, i = 0.01f, r0 = r0m;

  float best = -1.0f; int bi = 0;
  float plg = 0.0f, sd = 0.0f, sd2 = 0.0f;

  if (FLY) {
    for (int t = 0; t < TSAVES; ++t) {
#pragma unroll 10
      for (int j = 0; j < SPSAVE; ++j) {
        uint32_t n = (uint32_t)(t * SPSAVE + j) * (uint32_t)NB + (uint32_t)b;
        float dw = bits_to_dw(rand_bits32(kn0, kn1, n));
        float ni = (r0 * prec) * s;
        float nr = prec * i;
        float s_n = s - 0.01f * ni;
        float i_n = i + 0.01f * (ni - nr);
        float r0_n = (r0 + dtmr * (r0m - r0)) + ((sqrtf(fabsf(r0)) * pvol) * dw);
        s = s_n; i = i_n; r0 = r0_n;
      }
      float v = i;
      if (!isfinite(v)) v = 0.0f;
      float x = fmaxf(v, 1e-05f);
      if (x > best) { best = x; bi = t; }
      float lg = logf(x);
      if (t > 0) { float d = lg - plg; sd += d; sd2 += d * d; }
      plg = lg;
    }
  } else {
    // Single wave per CU -> wall time == per-wave serial chain time. The step
    // is rewritten for minimal op count (11) and minimal recurrence depth:
    // r0->r0: sub/fma + sqrt/fma (~3 dep ops); s->s, i->i: 2-3 dep ops.
    // fma reassociation is within measured numeric slack.
    const float* pb = noise + b;
    float q0[25], q1[25], q2[25], q3[25];
#define ISSUE(buf, s0) { \
    const int s0c = ((s0) > NSTEPS - 25) ? (NSTEPS - 25) : (s0); \
    _Pragma("unroll") \
    for (int k = 0; k < 25; ++k) buf[k] = pb[(size_t)(s0c + k) * NB]; \
    __builtin_amdgcn_sched_barrier(0); }
#define CGRP(buf) { \
    _Pragma("unroll") \
    for (int k = 0; k < 25; ++k) { \
      float vdw = buf[k] * pvol; \
      float dr  = r0m - r0; \
      float sq  = __builtin_amdgcn_sqrtf(fabsf(r0)); \
      float r0h = fmaf(dtmr, dr, r0); \
      float ni  = (r0 * prec) * s; \
      float nr  = prec * i; \
      float r0n = fmaf(sq, vdw, r0h); \
      float s_n = fmaf(-0.01f, ni, s); \
      float i_n = fmaf(0.01f, ni - nr, i); \
      s = s_n; i = i_n; r0 = r0n; \
    } \
    __builtin_amdgcn_sched_barrier(0); }

    ISSUE(q0, 0);
    ISSUE(q1, 25);
    ISSUE(q2, 50);
    for (int t = 0; t < TSAVES; ++t) {
      const int base = t * SPSAVE;
      ISSUE(q3, base + 75);  CGRP(q0);
      ISSUE(q0, base + 100); CGRP(q1);
      ISSUE(q1, base + 125); CGRP(q2);
      ISSUE(q2, base + 150); CGRP(q3);
      // save i, nan_to_num, streaming summarize
      float v = i;
      if (!isfinite(v)) v = 0.0f;
      float x = fmaxf(v, 1e-05f);
      if (x > best) { best = x; bi = t; }
      float lg = __builtin_amdgcn_logf(x) * 0.6931472f;
      if (t > 0) { float d = lg - plg; sd += d; sd2 += d * d; }
      plg = lg;
    }
#undef ISSUE
#undef CGRP
  }

  // u = uniform(k_u, (B,)) in [0,1): bits = y0^y1 of tf(ku, (0, b))
  uint32_t ub = rand_bits32(ku0, ku1, (uint32_t)b);
  float u = __uint_as_float((ub >> 9) | 0x3f800000u) - 1.0f;
  u = fmaxf(0.0f, u);

  float maxat = ((float)bi + u) / 49.0f;
  float mean = sd / 48.0f;
  float var = sd2 / 48.0f - mean * mean;
  float stdv = sqrtf(fmaxf(var, 0.0f));

  out[b * 3 + 0] = (best  - 0.38f) / 0.14f;
  out[b * 3 + 1] = (maxat - 0.21f) / 0.12f;
  out[b * 3 + 2] = (stdv  - 0.14f) / 0.03f;
}

extern "C" void kernel_launch(void* const* d_in, const int* in_sizes, int n_in,
                              void* d_out, int out_size, void* d_ws, size_t ws_size,
                              hipStream_t stream) {
  const float* cond = (const float*)d_in[0];
  const int* seedp = (const int*)d_in[1];
  float* out = (float*)d_out;
  float* noise = (float*)d_ws;
  const size_t need = (size_t)NTOT * sizeof(float);
  if (ws_size >= need) {
    gen_noise_kernel<<<GEN_BLOCKS, 256, 0, stream>>>(seedp, noise);
    sim_kernel<false><<<NB / 64, 64, 0, stream>>>(cond, seedp, noise, out);
  } else {
    sim_kernel<true><<<NB / 64, 64, 0, stream>>>(cond, seedp, nullptr, out);
  }
}

// Round 7
// 206.036 us; speedup vs baseline: 2.9322x; 1.3810x over previous
//
#include <hip/hip_runtime.h>
#include <cstdint>

// XLA emits separate mul/add; keep contraction off by default. Hot paths use
// explicit fmaf()/hw-transcendentals — measured-safe (absmax pinned at
// 1.038459e34 across 4 rounds of ulp-level arithmetic changes; slack ~3.5x).
#pragma clang fp contract(off)

#define TSAVES 49
#define SPSAVE 100
#define NB 8192
#define NSTEPS (TSAVES * SPSAVE)   // 4900
#define NTOT (NSTEPS * NB)         // 40140800

typedef float f32x4 __attribute__((ext_vector_type(4)));

__device__ __forceinline__ uint32_t rotl32(uint32_t v, int d) {
  return (v << d) | (v >> (32 - d));
}

// JAX threefry2x32, 20 rounds.
__device__ __forceinline__ void tf2x32(uint32_t k0, uint32_t k1,
                                       uint32_t x0, uint32_t x1,
                                       uint32_t& o0, uint32_t& o1) {
  uint32_t ks2 = k0 ^ k1 ^ 0x1BD11BDAu;
#define TF_ROUND(r) { x0 += x1; x1 = rotl32(x1, r); x1 ^= x0; }
  x0 += k0; x1 += k1;
  TF_ROUND(13) TF_ROUND(15) TF_ROUND(26) TF_ROUND(6)
  x0 += k1; x1 += ks2 + 1u;
  TF_ROUND(17) TF_ROUND(29) TF_ROUND(16) TF_ROUND(24)
  x0 += ks2; x1 += k0 + 2u;
  TF_ROUND(13) TF_ROUND(15) TF_ROUND(26) TF_ROUND(6)
  x0 += k0; x1 += k1 + 3u;
  TF_ROUND(17) TF_ROUND(29) TF_ROUND(16) TF_ROUND(24)
  x0 += k1; x1 += ks2 + 4u;
  TF_ROUND(13) TF_ROUND(15) TF_ROUND(26) TF_ROUND(6)
  x0 += ks2; x1 += k0 + 5u;
#undef TF_ROUND
  o0 = x0; o1 = x1;
}

// jax.random.split(key(seed)), jax_threefry_partitionable=True (fold-like).
__device__ __forceinline__ void derive_keys(int seed, uint32_t& kn0, uint32_t& kn1,
                                            uint32_t& ku0, uint32_t& ku1) {
  uint64_t s = (uint64_t)(int64_t)seed;
  uint32_t k0 = (uint32_t)(s >> 32);
  uint32_t k1 = (uint32_t)(s & 0xffffffffULL);
  tf2x32(k0, k1, 0u, 0u, kn0, kn1);  // keys[0] = k_noise
  tf2x32(k0, k1, 0u, 1u, ku0, ku1);  // keys[1] = k_u
}

// partitionable random_bits(32): counter = (hi=0, lo=n); bits = y0 ^ y1.
__device__ __forceinline__ uint32_t rand_bits32(uint32_t k0, uint32_t k1, uint32_t n) {
  uint32_t y0, y1;
  tf2x32(k0, k1, 0u, n, y0, y1);
  return y0 ^ y1;
}

// bits -> dw; XLA ErfInv32 (Giles). Branchy tail (execz-skipped ~80% of waves).
__device__ __forceinline__ float bits_to_dw(uint32_t bits) {
#pragma clang fp contract(fast)
  float u01 = __uint_as_float((bits >> 9) | 0x3f800000u) - 1.0f;
  float u = u01 * 2.0f + (-0.99999994f);
  u = fmaxf(-0.99999994f, u);
  float omu2 = 1.0f - u * u;                       // fma(-u,u,1)
  float w = -(__builtin_amdgcn_logf(omu2) * 0.6931472f);  // v_log (log2) * ln2
  float p;
  if (w < 5.0f) {
    float z = w - 2.5f;
    p = 2.81022636e-08f;
    p = 3.43273939e-07f + p * z;
    p = -3.5233877e-06f + p * z;
    p = -4.39150654e-06f + p * z;
    p = 0.00021858087f + p * z;
    p = -0.00125372503f + p * z;
    p = -0.00417768164f + p * z;
    p = 0.246640727f + p * z;
    p = 1.50140941f + p * z;
  } else {
    float z = __builtin_amdgcn_sqrtf(w) - 3.0f;
    p = -0.000200214257f;
    p = 0.000100950558f + p * z;
    p = 0.00134934322f + p * z;
    p = -0.00367342844f + p * z;
    p = 0.00573950773f + p * z;
    p = -0.0076224613f + p * z;
    p = 0.00943887047f + p * z;
    p = 1.00167406f + p * z;
    p = 2.83297682f + p * z;
  }
  float ei = p * u;
  float nrm = 1.41421356f * ei;  // f32(np.sqrt(2))
  return nrm * 0.1f;             // * sqrt(f32(0.01)) == 0.1f exactly
}

#define GEN_BLOCKS 4096
// 4-step-chunked layout: noise4[c*NB + b] = {dw(4c,b), dw(4c+1,b), dw(4c+2,b),
// dw(4c+3,b)}. Gen: one float4 store/thread, coalesced (consecutive b).
// Sim: one float4 load per 4 steps, coalesced. Same dw values, same order.
__global__ __launch_bounds__(256) void gen_noise_kernel(const int* __restrict__ seedp,
                                                        float* __restrict__ noise) {
  uint64_t sdv = (uint64_t)(int64_t)seedp[0];
  uint32_t k0 = (uint32_t)(sdv >> 32), k1 = (uint32_t)sdv;
  uint32_t kn0, kn1;
  tf2x32(k0, k1, 0u, 0u, kn0, kn1);
  const uint32_t stride = GEN_BLOCKS * 256u;
  for (uint32_t q = blockIdx.x * 256u + threadIdx.x; q < (uint32_t)(NTOT / 4); q += stride) {
    uint32_t c = q >> 13;             // chunk (4 consecutive steps)
    uint32_t b = q & 8191u;           // trajectory
    uint32_t n0 = (4u * c) * (uint32_t)NB + b;
    float4 o;
    o.x = bits_to_dw(rand_bits32(kn0, kn1, n0));
    o.y = bits_to_dw(rand_bits32(kn0, kn1, n0 + (uint32_t)NB));
    o.z = bits_to_dw(rand_bits32(kn0, kn1, n0 + 2u * (uint32_t)NB));
    o.w = bits_to_dw(rand_bits32(kn0, kn1, n0 + 3u * (uint32_t)NB));
    *reinterpret_cast<float4*>(noise + (size_t)q * 4) = o;
  }
}

__device__ __forceinline__ float clip_param(float x) {
  return fminf(0.99999988f, fmaxf(1e-07f, x));
}

template <bool FLY>
__global__ __launch_bounds__(64, 1) void sim_kernel(const float* __restrict__ cond,
                                                    const int* __restrict__ seedp,
                                                    const float* __restrict__ noise,
                                                    float* __restrict__ out) {
  const int lane = threadIdx.x;
  const int b = blockIdx.x * 64 + lane;

  uint32_t kn0, kn1, ku0, ku1;
  derive_keys(seedp[0], kn0, kn1, ku0, ku1);

  float pinf = clip_param(cond[b * 4 + 0]);
  float prec = clip_param(cond[b * 4 + 1]);
  float pmr  = clip_param(cond[b * 4 + 2]);
  float pvol = clip_param(cond[b * 4 + 3]);

  float r0m = pinf / prec;
  float dtmr = 0.01f * pmr;

  float s = 0.99f, i = 0.01f, r0 = r0m;

  float best = -1.0f; int bi = 0;
  float plg = 0.0f, sd = 0.0f, sd2 = 0.0f;

  if (FLY) {
    for (int t = 0; t < TSAVES; ++t) {
#pragma unroll 10
      for (int j = 0; j < SPSAVE; ++j) {
        uint32_t n = (uint32_t)(t * SPSAVE + j) * (uint32_t)NB + (uint32_t)b;
        float dw = bits_to_dw(rand_bits32(kn0, kn1, n));
        float ni = (r0 * prec) * s;
        float nr = prec * i;
        float s_n = s - 0.01f * ni;
        float i_n = i + 0.01f * (ni - nr);
        float r0_n = (r0 + dtmr * (r0m - r0)) + ((sqrtf(fabsf(r0)) * pvol) * dw);
        s = s_n; i = i_n; r0 = r0_n;
      }
      float v = i;
      if (!isfinite(v)) v = 0.0f;
      float x = fmaxf(v, 1e-05f);
      if (x > best) { best = x; bi = t; }
      float lg = logf(x);
      if (t > 0) { float d = lg - plg; sd += d; sd2 += d * d; }
      plg = lg;
    }
  } else {
    // Wall time == per-wave serial chain time (1 wave/CU). Loads: 25 dwordx4
    // per 100-step block, double-buffered; peak outstanding = 50 <= 63 vmcnt
    // hw cap (round-6 diagnosis: 100 outstanding scalar loads stalled issue).
    // Prefetch distance = 1 block (~3000 cy) >> ~900 cy HBM latency.
    const f32x4* pb4 = reinterpret_cast<const f32x4*>(noise) + b;
    f32x4 qA[25], qB[25];
#define ISSUE4(buf, g) { \
    _Pragma("unroll") \
    for (int m = 0; m < 25; ++m) buf[m] = pb4[(size_t)((g) * 25 + m) * NB]; \
    __builtin_amdgcn_sched_barrier(0); }
    // One Euler step, fma form (round-5/6 validated), static float4 lanes.
#define CGRP4(buf) { \
    _Pragma("unroll") \
    for (int j = 0; j < SPSAVE; ++j) { \
      float vdw = buf[j >> 2][j & 3] * pvol; \
      float dr  = r0m - r0; \
      float sq  = __builtin_amdgcn_sqrtf(fabsf(r0)); \
      float r0h = fmaf(dtmr, dr, r0); \
      float ni  = (r0 * prec) * s; \
      float nr  = prec * i; \
      float r0n = fmaf(sq, vdw, r0h); \
      float s_n = fmaf(-0.01f, ni, s); \
      float i_n = fmaf(0.01f, ni - nr, i); \
      s = s_n; i = i_n; r0 = r0n; \
    } \
    __builtin_amdgcn_sched_barrier(0); }
#define SAVE(t) { \
    float v = i; \
    if (!isfinite(v)) v = 0.0f; \
    float x = fmaxf(v, 1e-05f); \
    if (x > best) { best = x; bi = (t); } \
    float lg = __builtin_amdgcn_logf(x) * 0.6931472f; \
    if ((t) > 0) { float d = lg - plg; sd += d; sd2 += d * d; } \
    plg = lg; }

    ISSUE4(qA, 0);
    for (int t = 0; t < TSAVES - 1; t += 2) {
      ISSUE4(qB, t + 1); CGRP4(qA); SAVE(t);
      ISSUE4(qA, t + 2); CGRP4(qB); SAVE(t + 1);
    }
    CGRP4(qA); SAVE(TSAVES - 1);
#undef ISSUE4
#undef CGRP4
#undef SAVE
  }

  // u = uniform(k_u, (B,)) in [0,1): bits = y0^y1 of tf(ku, (0, b))
  uint32_t ub = rand_bits32(ku0, ku1, (uint32_t)b);
  float u = __uint_as_float((ub >> 9) | 0x3f800000u) - 1.0f;
  u = fmaxf(0.0f, u);

  float maxat = ((float)bi + u) / 49.0f;
  float mean = sd / 48.0f;
  float var = sd2 / 48.0f - mean * mean;
  float stdv = sqrtf(fmaxf(var, 0.0f));

  out[b * 3 + 0] = (best  - 0.38f) / 0.14f;
  out[b * 3 + 1] = (maxat - 0.21f) / 0.12f;
  out[b * 3 + 2] = (stdv  - 0.14f) / 0.03f;
}

extern "C" void kernel_launch(void* const* d_in, const int* in_sizes, int n_in,
                              void* d_out, int out_size, void* d_ws, size_t ws_size,
                              hipStream_t stream) {
  const float* cond = (const float*)d_in[0];
  const int* seedp = (const int*)d_in[1];
  float* out = (float*)d_out;
  float* noise = (float*)d_ws;
  const size_t need = (size_t)NTOT * sizeof(float);
  if (ws_size >= need) {
    gen_noise_kernel<<<GEN_BLOCKS, 256, 0, stream>>>(seedp, noise);
    sim_kernel<false><<<NB / 64, 64, 0, stream>>>(cond, seedp, noise, out);
  } else {
    sim_kernel<true><<<NB / 64, 64, 0, stream>>>(cond, seedp, nullptr, out);
  }
}

// Round 8
// 183.058 us; speedup vs baseline: 3.3003x; 1.1255x over previous
//
#include <hip/hip_runtime.h>
#include <cstdint>

// XLA emits separate mul/add; contraction off by default. Hot paths use
// explicit fmaf()/hw-transcendentals — measured-safe (absmax pinned at
// 1.038459e34 across 5 rounds of ulp-level arithmetic changes; slack ~4.5x).
#pragma clang fp contract(off)

#define TSAVES 49
#define SPSAVE 100
#define NB 8192
#define NSTEPS (TSAVES * SPSAVE)   // 4900
#define NTOT (NSTEPS * NB)         // 40140800

typedef float f32x4 __attribute__((ext_vector_type(4)));

// Force v_alignbit_b32 (round-7 theory: shift-or wasn't pattern-matched).
__device__ __forceinline__ uint32_t rotl32(uint32_t v, int d) {
  return __builtin_rotateleft32(v, (uint32_t)d);
}

// JAX threefry2x32, 20 rounds.
__device__ __forceinline__ void tf2x32(uint32_t k0, uint32_t k1,
                                       uint32_t x0, uint32_t x1,
                                       uint32_t& o0, uint32_t& o1) {
  uint32_t ks2 = k0 ^ k1 ^ 0x1BD11BDAu;
#define TF_ROUND(r) { x0 += x1; x1 = rotl32(x1, r); x1 ^= x0; }
  x0 += k0; x1 += k1;
  TF_ROUND(13) TF_ROUND(15) TF_ROUND(26) TF_ROUND(6)
  x0 += k1; x1 += ks2 + 1u;
  TF_ROUND(17) TF_ROUND(29) TF_ROUND(16) TF_ROUND(24)
  x0 += ks2; x1 += k0 + 2u;
  TF_ROUND(13) TF_ROUND(15) TF_ROUND(26) TF_ROUND(6)
  x0 += k0; x1 += k1 + 3u;
  TF_ROUND(17) TF_ROUND(29) TF_ROUND(16) TF_ROUND(24)
  x0 += k1; x1 += ks2 + 4u;
  TF_ROUND(13) TF_ROUND(15) TF_ROUND(26) TF_ROUND(6)
  x0 += ks2; x1 += k0 + 5u;
#undef TF_ROUND
  o0 = x0; o1 = x1;
}

// jax.random.split(key(seed)), jax_threefry_partitionable=True (fold-like).
__device__ __forceinline__ void derive_keys(int seed, uint32_t& kn0, uint32_t& kn1,
                                            uint32_t& ku0, uint32_t& ku1) {
  uint64_t s = (uint64_t)(int64_t)seed;
  uint32_t k0 = (uint32_t)(s >> 32);
  uint32_t k1 = (uint32_t)(s & 0xffffffffULL);
  tf2x32(k0, k1, 0u, 0u, kn0, kn1);  // keys[0] = k_noise
  tf2x32(k0, k1, 0u, 1u, ku0, ku1);  // keys[1] = k_u
}

// partitionable random_bits(32): counter = (hi=0, lo=n); bits = y0 ^ y1.
__device__ __forceinline__ uint32_t rand_bits32(uint32_t k0, uint32_t k1, uint32_t n) {
  uint32_t y0, y1;
  tf2x32(k0, k1, 0u, n, y0, y1);
  return y0 ^ y1;
}

// bits -> dw; XLA ErfInv32 (Giles). Branchy tail (execz-skipped ~96% of waves).
__device__ __forceinline__ float bits_to_dw(uint32_t bits) {
#pragma clang fp contract(fast)
  float u01 = __uint_as_float((bits >> 9) | 0x3f800000u) - 1.0f;
  float u = u01 * 2.0f + (-0.99999994f);
  u = fmaxf(-0.99999994f, u);
  float omu2 = 1.0f - u * u;                       // fma(-u,u,1)
  float w = -(__builtin_amdgcn_logf(omu2) * 0.6931472f);  // v_log (log2) * ln2
  float p;
  if (w < 5.0f) {
    float z = w - 2.5f;
    p = 2.81022636e-08f;
    p = 3.43273939e-07f + p * z;
    p = -3.5233877e-06f + p * z;
    p = -4.39150654e-06f + p * z;
    p = 0.00021858087f + p * z;
    p = -0.00125372503f + p * z;
    p = -0.00417768164f + p * z;
    p = 0.246640727f + p * z;
    p = 1.50140941f + p * z;
  } else {
    float z = __builtin_amdgcn_sqrtf(w) - 3.0f;
    p = -0.000200214257f;
    p = 0.000100950558f + p * z;
    p = 0.00134934322f + p * z;
    p = -0.00367342844f + p * z;
    p = 0.00573950773f + p * z;
    p = -0.0076224613f + p * z;
    p = 0.00943887047f + p * z;
    p = 1.00167406f + p * z;
    p = 2.83297682f + p * z;
  }
  float ei = p * u;
  float nrm = 1.41421356f * ei;  // f32(np.sqrt(2))
  return nrm * 0.1f;             // * sqrt(f32(0.01)) == 0.1f exactly
}

__device__ __forceinline__ float clip_param(float x) {
  return fminf(0.99999988f, fmaxf(1e-07f, x));
}

#define GEN_BLOCKS 4096
// 4-step-chunked layout with pvol folded in: noise4[c*NB+b] = dw(4c+k, b) *
// pvol[b], k=0..3. Same mul (dw*pvol) sim did in r5-r7 — bit-identical values.
__global__ __launch_bounds__(256) void gen_noise_kernel(const float* __restrict__ cond,
                                                        const int* __restrict__ seedp,
                                                        float* __restrict__ noise) {
  uint64_t sdv = (uint64_t)(int64_t)seedp[0];
  uint32_t k0 = (uint32_t)(sdv >> 32), k1 = (uint32_t)sdv;
  uint32_t kn0, kn1;
  tf2x32(k0, k1, 0u, 0u, kn0, kn1);
  const uint32_t stride = GEN_BLOCKS * 256u;
  for (uint32_t q = blockIdx.x * 256u + threadIdx.x; q < (uint32_t)(NTOT / 4); q += stride) {
    uint32_t c = q >> 13;             // chunk (4 consecutive steps)
    uint32_t b = q & 8191u;           // trajectory
    float pv = clip_param(cond[b * 4 + 3]);
    uint32_t n0 = (4u * c) * (uint32_t)NB + b;
    float4 o;
    o.x = bits_to_dw(rand_bits32(kn0, kn1, n0)) * pv;
    o.y = bits_to_dw(rand_bits32(kn0, kn1, n0 + (uint32_t)NB)) * pv;
    o.z = bits_to_dw(rand_bits32(kn0, kn1, n0 + 2u * (uint32_t)NB)) * pv;
    o.w = bits_to_dw(rand_bits32(kn0, kn1, n0 + 3u * (uint32_t)NB)) * pv;
    *reinterpret_cast<float4*>(noise + (size_t)q * 4) = o;
  }
}

template <bool FLY>
__global__ __launch_bounds__(64, 1) void sim_kernel(const float* __restrict__ cond,
                                                    const int* __restrict__ seedp,
                                                    const float* __restrict__ noise,
                                                    float* __restrict__ out) {
  const int lane = threadIdx.x;
  const int b = blockIdx.x * 64 + lane;

  uint32_t kn0, kn1, ku0, ku1;
  derive_keys(seedp[0], kn0, kn1, ku0, ku1);

  float pinf = clip_param(cond[b * 4 + 0]);
  float prec = clip_param(cond[b * 4 + 1]);
  float pmr  = clip_param(cond[b * 4 + 2]);
  float pvol = clip_param(cond[b * 4 + 3]);

  float r0m = pinf / prec;
  float dtmr = 0.01f * pmr;

  float s = 0.99f, i = 0.01f, r0 = r0m;

  float best = -1.0f; int bi = 0;
  float plg = 0.0f, sd = 0.0f, sd2 = 0.0f;

  if (FLY) {
    for (int t = 0; t < TSAVES; ++t) {
#pragma unroll 10
      for (int j = 0; j < SPSAVE; ++j) {
        uint32_t n = (uint32_t)(t * SPSAVE + j) * (uint32_t)NB + (uint32_t)b;
        float dw = bits_to_dw(rand_bits32(kn0, kn1, n));
        float ni = (r0 * prec) * s;
        float nr = prec * i;
        float s_n = s - 0.01f * ni;
        float i_n = i + 0.01f * (ni - nr);
        float r0_n = (r0 + dtmr * (r0m - r0)) + ((sqrtf(fabsf(r0)) * pvol) * dw);
        s = s_n; i = i_n; r0 = r0_n;
      }
      float v = i;
      if (!isfinite(v)) v = 0.0f;
      float x = fmaxf(v, 1e-05f);
      if (x > best) { best = x; bi = t; }
      float lg = logf(x);
      if (t > 0) { float d = lg - plg; sd += d; sd2 += d * d; }
      plg = lg;
    }
  } else {
    // 7-op step via constant pre-folding (1-2 ulp reassociation, within
    // measured slack): r0h = (1-dtmr)*r0 + dtmr*r0m; s,i updates share rs.
    const float c2 = 0.01f * prec;   // dt*rec
    const float c3 = 1.0f - c2;
    const float c4 = 1.0f - dtmr;
    const float a4 = dtmr * r0m;

    const f32x4* pb4 = reinterpret_cast<const f32x4*>(noise) + b;
    f32x4 qA[25], qB[25];
#define ISSUE4(buf, g) { \
    _Pragma("unroll") \
    for (int m = 0; m < 25; ++m) buf[m] = pb4[(size_t)((g) * 25 + m) * NB]; \
    __builtin_amdgcn_sched_barrier(0); }
#define CGRP4(buf) { \
    _Pragma("unroll") \
    for (int j = 0; j < SPSAVE; ++j) { \
      float vdw = buf[j >> 2][j & 3]; \
      float sq  = __builtin_amdgcn_sqrtf(fabsf(r0)); \
      float r0h = fmaf(c4, r0, a4); \
      float rs  = r0 * s; \
      float r0n = fmaf(sq, vdw, r0h); \
      float s_n = fmaf(-c2, rs, s); \
      float i_n = fmaf(c2, rs, i * c3); \
      s = s_n; i = i_n; r0 = r0n; \
    } \
    __builtin_amdgcn_sched_barrier(0); }
#define SAVE(t) { \
    float v = i; \
    if (!isfinite(v)) v = 0.0f; \
    float x = fmaxf(v, 1e-05f); \
    if (x > best) { best = x; bi = (t); } \
    float lg = __builtin_amdgcn_logf(x) * 0.6931472f; \
    if ((t) > 0) { float d = lg - plg; sd += d; sd2 += d * d; } \
    plg = lg; }

    ISSUE4(qA, 0);
    for (int t = 0; t < TSAVES - 1; t += 2) {
      ISSUE4(qB, t + 1); CGRP4(qA); SAVE(t);
      ISSUE4(qA, t + 2); CGRP4(qB); SAVE(t + 1);
    }
    CGRP4(qA); SAVE(TSAVES - 1);
#undef ISSUE4
#undef CGRP4
#undef SAVE
  }

  // u = uniform(k_u, (B,)) in [0,1): bits = y0^y1 of tf(ku, (0, b))
  uint32_t ub = rand_bits32(ku0, ku1, (uint32_t)b);
  float u = __uint_as_float((ub >> 9) | 0x3f800000u) - 1.0f;
  u = fmaxf(0.0f, u);

  float maxat = ((float)bi + u) / 49.0f;
  float mean = sd / 48.0f;
  float var = sd2 / 48.0f - mean * mean;
  float stdv = sqrtf(fmaxf(var, 0.0f));

  out[b * 3 + 0] = (best  - 0.38f) / 0.14f;
  out[b * 3 + 1] = (maxat - 0.21f) / 0.12f;
  out[b * 3 + 2] = (stdv  - 0.14f) / 0.03f;
}

extern "C" void kernel_launch(void* const* d_in, const int* in_sizes, int n_in,
                              void* d_out, int out_size, void* d_ws, size_t ws_size,
                              hipStream_t stream) {
  const float* cond = (const float*)d_in[0];
  const int* seedp = (const int*)d_in[1];
  float* out = (float*)d_out;
  float* noise = (float*)d_ws;
  const size_t need = (size_t)NTOT * sizeof(float);
  if (ws_size >= need) {
    gen_noise_kernel<<<GEN_BLOCKS, 256, 0, stream>>>(cond, seedp, noise);
    sim_kernel<false><<<NB / 64, 64, 0, stream>>>(cond, seedp, noise, out);
  } else {
    sim_kernel<true><<<NB / 64, 64, 0, stream>>>(cond, seedp, nullptr, out);
  }
}

// Round 9
// 182.821 us; speedup vs baseline: 3.3046x; 1.0013x over previous
//
#include <hip/hip_runtime.h>
#include <cstdint>

// XLA emits separate mul/add; contraction off by default. Hot paths use
// explicit fmaf()/hw-transcendentals — measured-safe across 6 rounds.
#pragma clang fp contract(off)

#define TSAVES 49
#define SPSAVE 100
#define NB 8192
#define NSTEPS (TSAVES * SPSAVE)   // 4900
#define NTOT (NSTEPS * NB)         // 40140800

typedef float f32x4 __attribute__((ext_vector_type(4)));

__device__ __forceinline__ uint32_t rotl32(uint32_t v, int d) {
  return __builtin_rotateleft32(v, (uint32_t)d);
}

// JAX threefry2x32, 20 rounds.
__device__ __forceinline__ void tf2x32(uint32_t k0, uint32_t k1,
                                       uint32_t x0, uint32_t x1,
                                       uint32_t& o0, uint32_t& o1) {
  uint32_t ks2 = k0 ^ k1 ^ 0x1BD11BDAu;
#define TF_ROUND(r) { x0 += x1; x1 = rotl32(x1, r); x1 ^= x0; }
  x0 += k0; x1 += k1;
  TF_ROUND(13) TF_ROUND(15) TF_ROUND(26) TF_ROUND(6)
  x0 += k1; x1 += ks2 + 1u;
  TF_ROUND(17) TF_ROUND(29) TF_ROUND(16) TF_ROUND(24)
  x0 += ks2; x1 += k0 + 2u;
  TF_ROUND(13) TF_ROUND(15) TF_ROUND(26) TF_ROUND(6)
  x0 += k0; x1 += k1 + 3u;
  TF_ROUND(17) TF_ROUND(29) TF_ROUND(16) TF_ROUND(24)
  x0 += k1; x1 += ks2 + 4u;
  TF_ROUND(13) TF_ROUND(15) TF_ROUND(26) TF_ROUND(6)
  x0 += ks2; x1 += k0 + 5u;
#undef TF_ROUND
  o0 = x0; o1 = x1;
}

// jax.random.split(key(seed)), jax_threefry_partitionable=True (fold-like).
__device__ __forceinline__ void derive_keys(int seed, uint32_t& kn0, uint32_t& kn1,
                                            uint32_t& ku0, uint32_t& ku1) {
  uint64_t s = (uint64_t)(int64_t)seed;
  uint32_t k0 = (uint32_t)(s >> 32);
  uint32_t k1 = (uint32_t)(s & 0xffffffffULL);
  tf2x32(k0, k1, 0u, 0u, kn0, kn1);  // keys[0] = k_noise
  tf2x32(k0, k1, 0u, 1u, ku0, ku1);  // keys[1] = k_u
}

// partitionable random_bits(32): counter = (hi=0, lo=n); bits = y0 ^ y1.
__device__ __forceinline__ uint32_t rand_bits32(uint32_t k0, uint32_t k1, uint32_t n) {
  uint32_t y0, y1;
  tf2x32(k0, k1, 0u, n, y0, y1);
  return y0 ^ y1;
}

// bits -> dw; XLA ErfInv32 (Giles). Branchy tail (execz-skipped ~96% of waves).
__device__ __forceinline__ float bits_to_dw(uint32_t bits) {
#pragma clang fp contract(fast)
  float u01 = __uint_as_float((bits >> 9) | 0x3f800000u) - 1.0f;
  float u = u01 * 2.0f + (-0.99999994f);
  u = fmaxf(-0.99999994f, u);
  float omu2 = 1.0f - u * u;                       // fma(-u,u,1)
  float w = -(__builtin_amdgcn_logf(omu2) * 0.6931472f);  // v_log (log2) * ln2
  float p;
  if (w < 5.0f) {
    float z = w - 2.5f;
    p = 2.81022636e-08f;
    p = 3.43273939e-07f + p * z;
    p = -3.5233877e-06f + p * z;
    p = -4.39150654e-06f + p * z;
    p = 0.00021858087f + p * z;
    p = -0.00125372503f + p * z;
    p = -0.00417768164f + p * z;
    p = 0.246640727f + p * z;
    p = 1.50140941f + p * z;
  } else {
    float z = __builtin_amdgcn_sqrtf(w) - 3.0f;
    p = -0.000200214257f;
    p = 0.000100950558f + p * z;
    p = 0.00134934322f + p * z;
    p = -0.00367342844f + p * z;
    p = 0.00573950773f + p * z;
    p = -0.0076224613f + p * z;
    p = 0.00943887047f + p * z;
    p = 1.00167406f + p * z;
    p = 2.83297682f + p * z;
  }
  float ei = p * u;
  float nrm = 1.41421356f * ei;  // f32(np.sqrt(2))
  return nrm * 0.1f;             // * sqrt(f32(0.01)) == 0.1f exactly
}

__device__ __forceinline__ float clip_param(float x) {
  return fminf(0.99999988f, fmaxf(1e-07f, x));
}

#define GEN_BLOCKS 4096
// 4-step-chunked layout with pvol folded in: noise4[c*NB+b] = dw(4c+k, b) *
// pvol[b], k=0..3. (Known-good from round 8: 97 us, VALUBusy ~100%.)
__global__ __launch_bounds__(256) void gen_noise_kernel(const float* __restrict__ cond,
                                                        const int* __restrict__ seedp,
                                                        float* __restrict__ noise) {
  uint64_t sdv = (uint64_t)(int64_t)seedp[0];
  uint32_t k0 = (uint32_t)(sdv >> 32), k1 = (uint32_t)sdv;
  uint32_t kn0, kn1;
  tf2x32(k0, k1, 0u, 0u, kn0, kn1);
  const uint32_t stride = GEN_BLOCKS * 256u;
  for (uint32_t q = blockIdx.x * 256u + threadIdx.x; q < (uint32_t)(NTOT / 4); q += stride) {
    uint32_t c = q >> 13;             // chunk (4 consecutive steps)
    uint32_t b = q & 8191u;           // trajectory
    float pv = clip_param(cond[b * 4 + 3]);
    uint32_t n0 = (4u * c) * (uint32_t)NB + b;
    float4 o;
    o.x = bits_to_dw(rand_bits32(kn0, kn1, n0)) * pv;
    o.y = bits_to_dw(rand_bits32(kn0, kn1, n0 + (uint32_t)NB)) * pv;
    o.z = bits_to_dw(rand_bits32(kn0, kn1, n0 + 2u * (uint32_t)NB)) * pv;
    o.w = bits_to_dw(rand_bits32(kn0, kn1, n0 + 3u * (uint32_t)NB)) * pv;
    *reinterpret_cast<float4*>(noise + (size_t)q * 4) = o;
  }
}

template <bool FLY>
__global__ __launch_bounds__(64, 1) void sim_kernel(const float* __restrict__ cond,
                                                    const int* __restrict__ seedp,
                                                    const float* __restrict__ noise,
                                                    float* __restrict__ out) {
  const int lane = threadIdx.x;
  const int b = blockIdx.x * 64 + lane;

  uint32_t kn0, kn1, ku0, ku1;
  derive_keys(seedp[0], kn0, kn1, ku0, ku1);

  float pinf = clip_param(cond[b * 4 + 0]);
  float prec = clip_param(cond[b * 4 + 1]);
  float pmr  = clip_param(cond[b * 4 + 2]);
  float pvol = clip_param(cond[b * 4 + 3]);

  float r0m = pinf / prec;
  float dtmr = 0.01f * pmr;

  float s = 0.99f, i = 0.01f, r0 = r0m;

  float best = -1.0f; int bi = 0;
  float plg = 0.0f, sd = 0.0f, sd2 = 0.0f;

  if (FLY) {
    for (int t = 0; t < TSAVES; ++t) {
#pragma unroll 10
      for (int j = 0; j < SPSAVE; ++j) {
        uint32_t n = (uint32_t)(t * SPSAVE + j) * (uint32_t)NB + (uint32_t)b;
        float dw = bits_to_dw(rand_bits32(kn0, kn1, n));
        float ni = (r0 * prec) * s;
        float nr = prec * i;
        float s_n = s - 0.01f * ni;
        float i_n = i + 0.01f * (ni - nr);
        float r0_n = (r0 + dtmr * (r0m - r0)) + ((sqrtf(fabsf(r0)) * pvol) * dw);
        s = s_n; i = i_n; r0 = r0_n;
      }
      float v = i;
      if (!isfinite(v)) v = 0.0f;
      float x = fmaxf(v, 1e-05f);
      if (x > best) { best = x; bi = t; }
      float lg = logf(x);
      if (t > 0) { float d = lg - plg; sd += d; sd2 += d * d; }
      plg = lg;
    }
  } else {
    // Round-9 structure: 5 buffers x 5 float4 (20 steps each). Live buffer
    // regs = 100 (fits: no spill/sink — round-8's 200-live forced VGPR=116
    // which contradicted the pinned pipeline). Loop body ~6 KB (I-cache
    // resident vs 24 KB before). Prefetch distance = 4 groups (80 steps
    // ~2000 cy) >> LLC/HBM latency; peak outstanding = 20 <= 63 vmcnt cap.
    // Arithmetic identical to round 8 (7-op fma step).
    const float c2 = 0.01f * prec;   // dt*rec
    const float c3 = 1.0f - c2;
    const float c4 = 1.0f - dtmr;
    const float a4 = dtmr * r0m;

    const f32x4* pb4 = reinterpret_cast<const f32x4*>(noise) + b;
    f32x4 q0[5], q1[5], q2[5], q3[5], q4[5];
#define ISSUE5(buf, g) { \
    _Pragma("unroll") \
    for (int m = 0; m < 5; ++m) buf[m] = pb4[(size_t)((g) * 5 + m) * NB]; \
    __builtin_amdgcn_sched_barrier(0); }
#define CGRP5(buf) { \
    _Pragma("unroll") \
    for (int j = 0; j < 20; ++j) { \
      float vdw = buf[j >> 2][j & 3]; \
      float sq  = __builtin_amdgcn_sqrtf(fabsf(r0)); \
      float r0h = fmaf(c4, r0, a4); \
      float rs  = r0 * s; \
      float r0n = fmaf(sq, vdw, r0h); \
      float s_n = fmaf(-c2, rs, s); \
      float i_n = fmaf(c2, rs, i * c3); \
      s = s_n; i = i_n; r0 = r0n; \
    } \
    __builtin_amdgcn_sched_barrier(0); }
#define SAVE(t) { \
    float v = i; \
    if (!isfinite(v)) v = 0.0f; \
    float x = fmaxf(v, 1e-05f); \
    if (x > best) { best = x; bi = (t); } \
    float lg = __builtin_amdgcn_logf(x) * 0.6931472f; \
    if ((t) > 0) { float d = lg - plg; sd += d; sd2 += d * d; } \
    plg = lg; }

    ISSUE5(q0, 0);
    ISSUE5(q1, 1);
    ISSUE5(q2, 2);
    ISSUE5(q3, 3);
    for (int t = 0; t < TSAVES - 1; ++t) {
      const int G = t * 5;
      ISSUE5(q4, G + 4); CGRP5(q0);
      ISSUE5(q0, G + 5); CGRP5(q1);
      ISSUE5(q1, G + 6); CGRP5(q2);
      ISSUE5(q2, G + 7); CGRP5(q3);
      ISSUE5(q3, G + 8); CGRP5(q4);
      SAVE(t);
    }
    // t = 48: groups 240..244; 244 was NOT yet issued (max issued = 243).
    ISSUE5(q4, 244); CGRP5(q0);
    CGRP5(q1);
    CGRP5(q2);
    CGRP5(q3);
    CGRP5(q4);
    SAVE(TSAVES - 1);
#undef ISSUE5
#undef CGRP5
#undef SAVE
  }

  // u = uniform(k_u, (B,)) in [0,1): bits = y0^y1 of tf(ku, (0, b))
  uint32_t ub = rand_bits32(ku0, ku1, (uint32_t)b);
  float u = __uint_as_float((ub >> 9) | 0x3f800000u) - 1.0f;
  u = fmaxf(0.0f, u);

  float maxat = ((float)bi + u) / 49.0f;
  float mean = sd / 48.0f;
  float var = sd2 / 48.0f - mean * mean;
  float stdv = sqrtf(fmaxf(var, 0.0f));

  out[b * 3 + 0] = (best  - 0.38f) / 0.14f;
  out[b * 3 + 1] = (maxat - 0.21f) / 0.12f;
  out[b * 3 + 2] = (stdv  - 0.14f) / 0.03f;
}

extern "C" void kernel_launch(void* const* d_in, const int* in_sizes, int n_in,
                              void* d_out, int out_size, void* d_ws, size_t ws_size,
                              hipStream_t stream) {
  const float* cond = (const float*)d_in[0];
  const int* seedp = (const int*)d_in[1];
  float* out = (float*)d_out;
  float* noise = (float*)d_ws;
  const size_t need = (size_t)NTOT * sizeof(float);
  if (ws_size >= need) {
    gen_noise_kernel<<<GEN_BLOCKS, 256, 0, stream>>>(cond, seedp, noise);
    sim_kernel<false><<<NB / 64, 64, 0, stream>>>(cond, seedp, noise, out);
  } else {
    sim_kernel<true><<<NB / 64, 64, 0, stream>>>(cond, seedp, nullptr, out);
  }
}